// Round 5
// baseline (499.571 us; speedup 1.0000x reference)
//
#include <hip/hip_runtime.h>
#include <math.h>

// Problem constants
constexpr int Nn = 64, Cc = 64, Tt = 300, Vv = 25, Ss = 3, Ii = 16, Oo = 64;
constexpr int TVc  = Tt * Vv;      // 7500
constexpr int CTVc = Cc * TVc;     // 480000 floats per n-slice of x
constexpr float KINV = 1.0f / 4800.0f;   // 1/(INTER*T)

// ws layout (floats)
constexpr int WS_ATT  = 0;         // N*S*25*25 = 120000
constexpr int WS_SUM  = 120000;    // 8 copies x 64
constexpr int WS_SQ   = 120512;    // 8 copies x 64
constexpr int WS_MEAN = 121024;    // 64
constexpr int WS_RSTD = 121088;    // 64
constexpr int WS_ZERO_FLOATS = 121024;   // att + sum + sq zeroed
constexpr int WS_XB_F   = 121152;  // xb bf16 [n][t*v][c]: 30,720,000 shorts
constexpr int WS_WAB_F  = WS_XB_F + 15360000;   // wab bf16 [3][32][64]
constexpr int WS_WDB_F  = WS_WAB_F + 3072;      // wdb bf16 [3][64][64]
constexpr int WS_ATTB_F = WS_WDB_F + 6144;      // attb bf16 [192][32][32]
constexpr int WS_END_F  = WS_ATTB_F + 98304;
constexpr size_t WS_NEED = (size_t)WS_END_F * 4;

typedef __attribute__((ext_vector_type(8))) short bf16x8;
typedef __attribute__((ext_vector_type(4))) short short4v;
typedef __attribute__((ext_vector_type(4))) float f32x4;
typedef __attribute__((ext_vector_type(16))) float f32x16;
typedef __attribute__((ext_vector_type(4))) int int4v;

__device__ __forceinline__ short f2bf(float f) {
    unsigned u = __builtin_bit_cast(unsigned, f);
    u += 0x7FFFu + ((u >> 16) & 1u);           // RNE
    return (short)(u >> 16);
}
__device__ __forceinline__ float bf2f(short s) {
    unsigned u = ((unsigned)(unsigned short)s) << 16;
    return __builtin_bit_cast(float, u);
}
__device__ __forceinline__ void store4(float* p, f32x4 v) {
    __builtin_memcpy(p, &v, 16);
}

// ---------------------------------------------------------------------------
// Kernel 0: x [n][c][t*v] f32 -> xb [n][t*v][c] bf16 (coalesced reads).
// ---------------------------------------------------------------------------
__global__ __launch_bounds__(256) void k0_xpose(
    const float* __restrict__ x, short* __restrict__ xb)
{
    const int n   = blockIdx.y;
    const int tid = threadIdx.x;
    const int tv  = blockIdx.x * 32 + (tid & 31);
    const int g   = (tid >> 5) & 7;
    if (tv >= TVc) return;
    const float* xp = x + (size_t)n * CTVc + (size_t)(g * 8) * TVc + tv;
    bf16x8 o;
    #pragma unroll
    for (int j = 0; j < 8; ++j) o[j] = f2bf(xp[(size_t)j * TVc]);
    *(bf16x8*)(xb + ((size_t)n * TVc + tv) * 64 + g * 8) = o;
}

// ---------------------------------------------------------------------------
// Kernel P: pack weights to bf16 once.
// wab [3][32][64]: rows 0-15 = Wa rows, 16-31 = Wb rows. wdb [3][64][64]=Wd.
// ---------------------------------------------------------------------------
__global__ __launch_bounds__(256) void kpack(
    const float* __restrict__ Wa, const float* __restrict__ Wb,
    const float* __restrict__ Wd, short* __restrict__ wab, short* __restrict__ wdb)
{
    const int i = blockIdx.x * 256 + threadIdx.x;
    if (i < 6144) {
        const int s = i >> 11, rb = i & 2047, r = rb >> 6, c = rb & 63;
        const float v = (r < 16) ? Wa[(s * 16 + r) * 64 + c]
                                 : Wb[(s * 16 + (r - 16)) * 64 + c];
        wab[i] = f2bf(v);
    }
    if (i < 12288) wdb[i] = f2bf(Wd[i]);
}

// ---------------------------------------------------------------------------
// Shared phase-1 B-fragment loader (xb bf16 coalesced vs f32 strided fallback)
// ---------------------------------------------------------------------------
template<bool XB>
__device__ __forceinline__ void load_xfrag(
    const float* __restrict__ xn, const short* __restrict__ xbn,
    int tv, bool ok, int quad, bf16x8& b0, bf16x8& b1)
{
    if constexpr (XB) {
        const short* bp = xbn + (ok ? tv : 0) * 64 + quad * 8;
        b0 = *(const bf16x8*)bp;
        b1 = *(const bf16x8*)(bp + 32);
    } else {
        const float* bp = xn + (quad * 8) * TVc + tv;
        #pragma unroll
        for (int j = 0; j < 8; ++j) {
            b0[j] = f2bf(ok ? bp[j * TVc] : 0.0f);
            b1[j] = f2bf(ok ? bp[(j + 32) * TVc] : 0.0f);
        }
    }
}

// ---------------------------------------------------------------------------
// Kernel A: MFMA conv + MFMA gram. Weight frags single L2 bf16 loads.
// ---------------------------------------------------------------------------
template<bool XB>
__global__ __launch_bounds__(256) void ka_gram_mfma(
    const float* __restrict__ x, const short* __restrict__ xb,
    const short* __restrict__ wab,
    const float* __restrict__ Wa, const float* __restrict__ ba,
    const float* __restrict__ Wb, const float* __restrict__ bb,
    float* __restrict__ att)
{
    __shared__ short uT[112 * 104];
    __shared__ float part[4 * 1024];
    __shared__ float bab[96];

    const int tid = threadIdx.x;
    const int t0  = blockIdx.x * 4;
    const int n   = blockIdx.y;
    const float* xn  = x + n * CTVc + t0 * 25;
    const short* xbn = XB ? (xb + ((size_t)n * TVc + t0 * 25) * 64) : nullptr;

    if (tid < 96) {
        const int s = tid >> 5, r = tid & 31;
        bab[tid] = (r < 16) ? ba[s * 16 + r] : bb[s * 16 + r - 16];
    }

    const int lane = tid & 63;
    const int wave = tid >> 6;
    const int l16  = lane & 15;
    const int quad = lane >> 4;

    bf16x8 afr[3][2][2];
    #pragma unroll
    for (int s = 0; s < 3; ++s)
        #pragma unroll
        for (int half = 0; half < 2; ++half)
            #pragma unroll
            for (int k = 0; k < 2; ++k) {
                if constexpr (XB) {
                    afr[s][half][k] = *(const bf16x8*)(
                        wab + (s * 32 + half * 16 + l16) * 64 + k * 32 + quad * 8);
                } else {
                    const float* W = half ? Wb : Wa;
                    const float* wp = W + (s * 16 + l16) * 64 + k * 32 + quad * 8;
                    const float4 w0 = *(const float4*)wp;
                    const float4 w1 = *(const float4*)(wp + 4);
                    bf16x8 a;
                    a[0] = f2bf(w0.x); a[1] = f2bf(w0.y); a[2] = f2bf(w0.z); a[3] = f2bf(w0.w);
                    a[4] = f2bf(w1.x); a[5] = f2bf(w1.y); a[6] = f2bf(w1.z); a[7] = f2bf(w1.w);
                    afr[s][half][k] = a;
                }
            }
    __syncthreads();

    for (int nt = wave; nt < 7; nt += 4) {
        const int tv = nt * 16 + l16;
        const bool ok = tv < 100;
        bf16x8 b0, b1;
        load_xfrag<XB>(xn, xbn, tv, ok, quad, b0, b1);
        #pragma unroll
        for (int s = 0; s < 3; ++s)
            #pragma unroll
            for (int half = 0; half < 2; ++half) {
                f32x4 acc = {0.0f, 0.0f, 0.0f, 0.0f};
                acc = __builtin_amdgcn_mfma_f32_16x16x32_bf16(afr[s][half][0], b0, acc, 0, 0, 0);
                acc = __builtin_amdgcn_mfma_f32_16x16x32_bf16(afr[s][half][1], b1, acc, 0, 0, 0);
                const float4 bv = *(const float4*)(bab + s * 32 + half * 16 + quad * 4);
                short4v pk;
                pk[0] = f2bf(acc[0] + bv.x); pk[1] = f2bf(acc[1] + bv.y);
                pk[2] = f2bf(acc[2] + bv.z); pk[3] = f2bf(acc[3] + bv.w);
                *(short4v*)(uT + tv * 104 + s * 32 + half * 16 + quad * 4) = pk;
            }
    }
    __syncthreads();

    const int t   = wave;
    const int w32 = lane & 31;
    const int khi = lane >> 5;
    f32x16 g[3];
    #pragma unroll
    for (int s = 0; s < 3; ++s)
        #pragma unroll
        for (int r = 0; r < 16; ++r) g[s][r] = 0.0f;

    #pragma unroll
    for (int s = 0; s < 3; ++s) {
        const short* base = uT + (t * 25 + w32) * 104 + s * 32 + khi * 8;
        const bf16x8 aA = *(const bf16x8*)(base);
        const bf16x8 bB = *(const bf16x8*)(base + 16);
        g[s] = __builtin_amdgcn_mfma_f32_32x32x16_bf16(aA, bB, g[s], 0, 0, 0);
    }

    for (int s = 0; s < 3; ++s) {
        __syncthreads();
        #pragma unroll
        for (int r = 0; r < 16; ++r) {
            const int row = (r & 3) + 8 * (r >> 2) + 4 * khi;
            part[wave * 1024 + row * 32 + w32] = g[s][r];
        }
        __syncthreads();
        float* attns = att + (n * 3 + s) * 625;
        for (int p = tid; p < 625; p += 256) {
            const int v = p / 25, w = p - v * 25;
            const int q = v * 32 + w;
            atomicAdd(attns + p, part[q] + part[1024 + q] + part[2048 + q] + part[3072 + q]);
        }
    }
}

// ---------------------------------------------------------------------------
// Kernel B: column softmax; also emits attb (bf16, transposed, 32x32 padded).
// ---------------------------------------------------------------------------
template<bool ATTB>
__global__ __launch_bounds__(64) void kb_softmax(
    float* __restrict__ att, const float* __restrict__ A, const float* __restrict__ PA,
    short* __restrict__ attb)
{
    const int b = blockIdx.x;
    const int s = b % 3;
    const int w = threadIdx.x;
    if (w >= 32) return;
    float col[25] = {};
    if (w < 25) {
        float* base = att + b * 625;
        float m = -1e30f;
        #pragma unroll
        for (int v = 0; v < 25; ++v) {
            col[v] = base[v * 25 + w] * KINV;
            m = fmaxf(m, col[v]);
        }
        float sum = 0.0f;
        #pragma unroll
        for (int v = 0; v < 25; ++v) { col[v] = expf(col[v] - m); sum += col[v]; }
        const float inv = 1.0f / sum;
        #pragma unroll
        for (int v = 0; v < 25; ++v) {
            col[v] = fmaf(col[v], inv, A[(s * 25 + v) * 25 + w] + PA[(s * 25 + v) * 25 + w]);
            base[v * 25 + w] = col[v];
        }
    }
    if constexpr (ATTB) {
        short* dst = attb + b * 1024 + w * 32;
        #pragma unroll
        for (int v = 0; v < 25; ++v) dst[v] = (w < 25) ? f2bf(col[v]) : (short)0;
        #pragma unroll
        for (int v = 25; v < 32; ++v) dst[v] = 0;
    }
}

// ---------------------------------------------------------------------------
// Kernel 3 (r4->r5): multi-tile pipelined. Grid (25, 64), 512 thr, 3 tiles/blk.
//  - U zeroed ONCE: written (row,col) slots are identical every tile (col
//    depends only on tv), pad cols never written -> stay 0.
//  - attb fragments hoisted (loop-invariant).
//  - xb fragment for tile it+1 prefetched before phase-1 MFMAs of tile it
//    (latency hides under MFMA + 2 barriers + phase 2).
//  - BN sums accumulate in regs across tiles; one reduce+atomic per block.
//  - launch_bounds(512,6): keep VGPR <= ~84 so LDS (51.2KB) stays the
//    occupancy limiter (3 blocks/CU).
// ---------------------------------------------------------------------------
constexpr int K3_TILES = 3;   // grid.x = 75 / K3_TILES = 25

__global__ __launch_bounds__(512, 6) void k3_y_mfma(
    const short* __restrict__ xb, const short* __restrict__ wdb,
    const short* __restrict__ attb, float* __restrict__ y, float* __restrict__ bns)
{
    __shared__ __align__(16) short U[192 * 128];     // 49.2 KB
    __shared__ float bnA[8][32], bnB[8][32];         // 2 KB

    const int tid = threadIdx.x;
    const int n   = blockIdx.y;
    const int tb0 = blockIdx.x * K3_TILES;           // tile idx; t0 = (tb0+it)*4

    const int lane = tid & 63;
    const int wave = tid >> 6;
    const int l16  = lane & 15;
    const int quad = lane >> 4;

    // zero ALL of U once (pad cols must be exact 0.0 for phase-2 K-dim)
    for (int i = tid; i < 3072; i += 512)
        ((int4v*)U)[i] = (int4v){0, 0, 0, 0};

    // loop-invariant attb fragments (phase 2)
    bf16x8 a0[3], a1[3];
    #pragma unroll
    for (int s = 0; s < 3; ++s) {
        const short* ab = attb + (size_t)(n * 3 + s) * 1024 + l16 * 32 + quad * 8;
        a0[s] = *(const bf16x8*)ab;
        a1[s] = *(const bf16x8*)(ab + 512);
    }

    // phase-1 geometry (constant per thread)
    const int tv  = (wave < 7) ? wave * 16 + l16 : 0;
    const bool ok = (wave < 7) && (tv < 100);
    const int tl  = tv / 25;
    const int vp  = tv - tl * 25;
    const int col = tl * 32 + vp;
    const int grp = col >> 3, ing = col & 7;

    const short* xtile = xb + ((size_t)n * TVc + tb0 * 100) * 64;
    const int xoff = (ok ? tv : 0) * 64 + quad * 8;

    // preload first tile's x fragment
    bf16x8 bc0 = *(const bf16x8*)(xtile + xoff);
    bf16x8 bc1 = *(const bf16x8*)(xtile + xoff + 32);
    bf16x8 nx0, nx1;

    const int t  = wave >> 1;
    const int ob = (wave & 1) * 32;
    float s1[2] = {0.0f, 0.0f}, s2[2] = {0.0f, 0.0f};

    __syncthreads();   // U zeroed before phase-1 stores

    #pragma unroll
    for (int it = 0; it < K3_TILES; ++it) {
        // prefetch next tile's x fragment (overlaps MFMA + barriers + phase 2)
        if (it + 1 < K3_TILES) {
            const short* bp = xtile + (it + 1) * 6400 + xoff;
            nx0 = *(const bf16x8*)bp;
            nx1 = *(const bf16x8*)(bp + 32);
        }

        // ---- phase 1 (waves 0..6) ----
        if (wave < 7) {
            #pragma unroll
            for (int s = 0; s < 3; ++s)
                #pragma unroll
                for (int m = 0; m < 4; ++m) {
                    const short* wp = wdb + (s * 64 + m * 16 + l16) * 64 + quad * 8;
                    const bf16x8 f0 = *(const bf16x8*)wp;
                    const bf16x8 f1 = *(const bf16x8*)(wp + 32);
                    f32x4 acc = {0.0f, 0.0f, 0.0f, 0.0f};
                    acc = __builtin_amdgcn_mfma_f32_16x16x32_bf16(f0, bc0, acc, 0, 0, 0);
                    acc = __builtin_amdgcn_mfma_f32_16x16x32_bf16(f1, bc1, acc, 0, 0, 0);
                    if (ok) {
                        #pragma unroll
                        for (int r = 0; r < 4; ++r) {
                            const int row = s * 64 + m * 16 + quad * 4 + r;
                            U[row * 128 + (((grp ^ (row & 15)) << 3) | ing)] = f2bf(acc[r]);
                        }
                    }
                }
        }
        __syncthreads();

        // ---- phase 2 ----
        f32x4 D[2][2];
        #pragma unroll
        for (int mt = 0; mt < 2; ++mt)
            #pragma unroll
            for (int nb = 0; nb < 2; ++nb) D[mt][nb] = (f32x4){0.0f, 0.0f, 0.0f, 0.0f};
        #pragma unroll
        for (int s = 0; s < 3; ++s) {
            #pragma unroll
            for (int nb = 0; nb < 2; ++nb) {
                const int row = s * 64 + ob + nb * 16 + l16;
                const bf16x8 bv = *(const bf16x8*)(
                    U + row * 128 + (((t * 4 + quad) ^ (row & 15)) << 3));
                D[0][nb] = __builtin_amdgcn_mfma_f32_16x16x32_bf16(a0[s], bv, D[0][nb], 0, 0, 0);
                D[1][nb] = __builtin_amdgcn_mfma_f32_16x16x32_bf16(a1[s], bv, D[1][nb], 0, 0, 0);
            }
        }

        // ---- y stores + BN accumulation ----
        const int t0 = (tb0 + it) * 4;
        #pragma unroll
        for (int nb = 0; nb < 2; ++nb) {
            const int og = ob + nb * 16 + l16;
            float* dst = y + ((size_t)(n * 64 + og) * 300 + t0 + t) * 25;
            const f32x4 d0 = D[0][nb];
            store4(dst + quad * 4, d0);
            s1[nb] += d0[0] + d0[1] + d0[2] + d0[3];
            s2[nb] += d0[0]*d0[0] + d0[1]*d0[1] + d0[2]*d0[2] + d0[3]*d0[3];
            const f32x4 d1 = D[1][nb];
            if (quad < 2) {
                store4(dst + 16 + quad * 4, d1);
                s1[nb] += d1[0] + d1[1] + d1[2] + d1[3];
                s2[nb] += d1[0]*d1[0] + d1[1]*d1[1] + d1[2]*d1[2] + d1[3]*d1[3];
            } else if (quad == 2) {
                dst[24] = d1[0];
                s1[nb] += d1[0];
                s2[nb] += d1[0] * d1[0];
            }
        }
        __syncthreads();   // U consumed; safe for next tile's phase-1 writes
        if (it + 1 < K3_TILES) { bc0 = nx0; bc1 = nx1; }
    }

    // ---- BN reduce once per block ----
    #pragma unroll
    for (int nb = 0; nb < 2; ++nb) {
        s1[nb] += __shfl_xor(s1[nb], 16); s1[nb] += __shfl_xor(s1[nb], 32);
        s2[nb] += __shfl_xor(s2[nb], 16); s2[nb] += __shfl_xor(s2[nb], 32);
    }
    if (lane < 16) {
        bnA[wave][lane]      = s1[0];
        bnA[wave][16 + lane] = s1[1];
        bnB[wave][lane]      = s2[0];
        bnB[wave][16 + lane] = s2[1];
    }
    __syncthreads();
    if (tid < 64) {
        const int o = tid, h = o >> 5, i = o & 31;
        const float S1 = bnA[h][i] + bnA[h + 2][i] + bnA[h + 4][i] + bnA[h + 6][i];
        const float S2 = bnB[h][i] + bnB[h + 2][i] + bnB[h + 4][i] + bnB[h + 6][i];
        const int cp = (blockIdx.x & 7) * 64;
        atomicAdd(bns + cp + o, S1);
        atomicAdd(bns + 512 + cp + o, S2);
    }
}

// ---------------------------------------------------------------------------
// Kernel 3 fallback (ws too small): round-1 structure, f32 inputs.
// ---------------------------------------------------------------------------
__global__ __launch_bounds__(256) void k3_y_mfma_fb(
    const float* __restrict__ x, const float* __restrict__ Wd,
    const float* __restrict__ att, float* __restrict__ y, float* __restrict__ bns)
{
    __shared__ __align__(16) short U[96 * 128];
    __shared__ __align__(16) short attT[3 * 1024];
    __shared__ float bn1[4][32], bn2[4][32];

    const int tid = threadIdx.x;
    const int t0  = blockIdx.x * 4;
    const int n   = blockIdx.y;
    const int oh  = blockIdx.z;
    const float* xn = x + n * CTVc + t0 * 25;

    const int lane = tid & 63;
    const int wave = tid >> 6;
    const int l16  = lane & 15;
    const int quad = lane >> 4;

    for (int i = tid; i < 1536; i += 256)
        ((int4v*)U)[i] = (int4v){0, 0, 0, 0};
    for (int i = tid; i < 3072; i += 256) {
        const int s = i >> 10, r = i & 1023, v = r >> 5, vp = r & 31;
        const float val = (v < 25 && vp < 25) ? att[(n * 3 + s) * 625 + vp * 25 + v] : 0.0f;
        attT[i] = f2bf(val);
    }
    bf16x8 afr[3][2][2];
    #pragma unroll
    for (int s = 0; s < 3; ++s)
        #pragma unroll
        for (int m = 0; m < 2; ++m)
            #pragma unroll
            for (int k = 0; k < 2; ++k) {
                const float* wp = Wd + ((s * 64 + oh * 32 + m * 16 + l16) * 64) + k * 32 + quad * 8;
                const float4 w0 = *(const float4*)wp;
                const float4 w1 = *(const float4*)(wp + 4);
                bf16x8 a;
                a[0] = f2bf(w0.x); a[1] = f2bf(w0.y); a[2] = f2bf(w0.z); a[3] = f2bf(w0.w);
                a[4] = f2bf(w1.x); a[5] = f2bf(w1.y); a[6] = f2bf(w1.z); a[7] = f2bf(w1.w);
                afr[s][m][k] = a;
            }
    __syncthreads();

    for (int nt = wave; nt < 7; nt += 4) {
        const int tv = nt * 16 + l16;
        const bool ok = tv < 100;
        bf16x8 b0, b1;
        load_xfrag<false>(xn, nullptr, tv, ok, quad, b0, b1);
        const int tl  = tv / 25;
        const int vp  = tv - tl * 25;
        const int col = tl * 32 + vp;
        const int grp = col >> 3, ing = col & 7;
        #pragma unroll
        for (int s = 0; s < 3; ++s)
            #pragma unroll
            for (int m = 0; m < 2; ++m) {
                f32x4 acc = {0.0f, 0.0f, 0.0f, 0.0f};
                acc = __builtin_amdgcn_mfma_f32_16x16x32_bf16(afr[s][m][0], b0, acc, 0, 0, 0);
                acc = __builtin_amdgcn_mfma_f32_16x16x32_bf16(afr[s][m][1], b1, acc, 0, 0, 0);
                if (ok) {
                    #pragma unroll
                    for (int r = 0; r < 4; ++r) {
                        const int row = s * 32 + m * 16 + quad * 4 + r;
                        U[row * 128 + (((grp ^ (row & 15)) << 3) | ing)] = f2bf(acc[r]);
                    }
                }
            }
    }
    __syncthreads();

    const int t = wave;
    bf16x8 aF[3][2], bF[3][2];
    #pragma unroll
    for (int s = 0; s < 3; ++s) {
        #pragma unroll
        for (int mt = 0; mt < 2; ++mt)
            aF[s][mt] = *(const bf16x8*)(attT + s * 1024 + (mt * 16 + l16) * 32 + quad * 8);
        #pragma unroll
        for (int nb = 0; nb < 2; ++nb) {
            const int row = s * 32 + nb * 16 + l16;
            bF[s][nb] = *(const bf16x8*)(U + row * 128 + (((t * 4 + quad) ^ (row & 15)) << 3));
        }
    }
    f32x4 D[2][2];
    #pragma unroll
    for (int mt = 0; mt < 2; ++mt)
        #pragma unroll
        for (int nb = 0; nb < 2; ++nb) D[mt][nb] = (f32x4){0.0f, 0.0f, 0.0f, 0.0f};
    #pragma unroll
    for (int s = 0; s < 3; ++s)
        #pragma unroll
        for (int mt = 0; mt < 2; ++mt)
            #pragma unroll
            for (int nb = 0; nb < 2; ++nb)
                D[mt][nb] = __builtin_amdgcn_mfma_f32_16x16x32_bf16(aF[s][mt], bF[s][nb], D[mt][nb], 0, 0, 0);

    float s1[2] = {0.0f, 0.0f}, s2[2] = {0.0f, 0.0f};
    #pragma unroll
    for (int nb = 0; nb < 2; ++nb) {
        const int og = oh * 32 + nb * 16 + l16;
        float* dst = y + ((size_t)(n * 64 + og) * 300 + t0 + t) * 25;
        const f32x4 d0 = D[0][nb];
        store4(dst + quad * 4, d0);
        s1[nb] += d0[0] + d0[1] + d0[2] + d0[3];
        s2[nb] += d0[0]*d0[0] + d0[1]*d0[1] + d0[2]*d0[2] + d0[3]*d0[3];
        const f32x4 d1 = D[1][nb];
        if (quad < 2) {
            store4(dst + 16 + quad * 4, d1);
            s1[nb] += d1[0] + d1[1] + d1[2] + d1[3];
            s2[nb] += d1[0]*d1[0] + d1[1]*d1[1] + d1[2]*d1[2] + d1[3]*d1[3];
        } else if (quad == 2) {
            dst[24] = d1[0];
            s1[nb] += d1[0];
            s2[nb] += d1[0] * d1[0];
        }
    }
    #pragma unroll
    for (int nb = 0; nb < 2; ++nb) {
        s1[nb] += __shfl_xor(s1[nb], 16); s1[nb] += __shfl_xor(s1[nb], 32);
        s2[nb] += __shfl_xor(s2[nb], 16); s2[nb] += __shfl_xor(s2[nb], 32);
    }
    if (lane < 16) {
        bn1[wave][lane]      = s1[0];
        bn1[wave][16 + lane] = s1[1];
        bn2[wave][lane]      = s2[0];
        bn2[wave][16 + lane] = s2[1];
    }
    __syncthreads();
    if (tid < 32) {
        const float S1 = bn1[0][tid] + bn1[1][tid] + bn1[2][tid] + bn1[3][tid];
        const float S2 = bn2[0][tid] + bn2[1][tid] + bn2[2][tid] + bn2[3][tid];
        const int cp = (blockIdx.x & 7) * 64;
        atomicAdd(bns + cp + oh * 32 + tid, S1);
        atomicAdd(bns + 512 + cp + oh * 32 + tid, S2);
    }
}

// ---------------------------------------------------------------------------
// Kernel 3b: finalize BN stats (8-copy reduction)
// ---------------------------------------------------------------------------
__global__ __launch_bounds__(64) void k3b_stats(float* __restrict__ ws)
{
    const int o = threadIdx.x;
    if (o >= 64) return;
    const float cnt_inv = 1.0f / 480000.0f;
    float s = 0.0f, q = 0.0f;
    #pragma unroll
    for (int j = 0; j < 8; ++j) {
        s += ws[WS_SUM + j * 64 + o];
        q += ws[WS_SQ  + j * 64 + o];
    }
    const float mean = s * cnt_inv;
    const float var  = q * cnt_inv - mean * mean;
    ws[WS_MEAN + o] = mean;
    ws[WS_RSTD + o] = rsqrtf(var + 1e-5f);
}

// ---------------------------------------------------------------------------
// Kernel 4: BN + residual + ReLU (3D grid, no integer div)
// ---------------------------------------------------------------------------
__global__ __launch_bounds__(256) void k4_bn(
    float* __restrict__ out, const float* __restrict__ x,
    const float* __restrict__ gamma, const float* __restrict__ beta,
    const float* __restrict__ ws)
{
    const int o = blockIdx.y, n = blockIdx.z;
    const int j = blockIdx.x * 256 + threadIdx.x;
    if (j >= 1875) return;
    const size_t i4 = (size_t)(n * 64 + o) * 1875 + j;
    const float mean = ws[WS_MEAN + o], rstd = ws[WS_RSTD + o];
    const float g = gamma[o], b = beta[o];
    const float4 yv = ((const float4*)out)[i4];
    const float4 xv = ((const float4*)x)[i4];
    float4 r;
    r.x = fmaxf(fmaf(g * (yv.x - mean), rstd, b) + xv.x, 0.0f);
    r.y = fmaxf(fmaf(g * (yv.y - mean), rstd, b) + xv.y, 0.0f);
    r.z = fmaxf(fmaf(g * (yv.z - mean), rstd, b) + xv.z, 0.0f);
    r.w = fmaxf(fmaf(g * (yv.w - mean), rstd, b) + xv.w, 0.0f);
    ((float4*)out)[i4] = r;
}

// ---------------------------------------------------------------------------
extern "C" void kernel_launch(void* const* d_in, const int* in_sizes, int n_in,
                              void* d_out, int out_size, void* d_ws, size_t ws_size,
                              hipStream_t stream)
{
    const float* x  = (const float*)d_in[0];
    const float* A  = (const float*)d_in[1];
    const float* PA = (const float*)d_in[2];
    const float* Wa = (const float*)d_in[3];
    const float* ba = (const float*)d_in[4];
    const float* Wb = (const float*)d_in[5];
    const float* bb = (const float*)d_in[6];
    const float* Wd = (const float*)d_in[7];
    const float* gamma = (const float*)d_in[9];
    const float* beta  = (const float*)d_in[10];
    float* out = (float*)d_out;
    float* ws  = (float*)d_ws;

    hipMemsetAsync(d_ws, 0, (size_t)WS_ZERO_FLOATS * sizeof(float), stream);

    if (ws_size >= WS_NEED) {
        short* xbp  = (short*)(ws + WS_XB_F);
        short* wab  = (short*)(ws + WS_WAB_F);
        short* wdb  = (short*)(ws + WS_WDB_F);
        short* attb = (short*)(ws + WS_ATTB_F);
        k0_xpose<<<dim3(235, 64), 256, 0, stream>>>(x, xbp);
        kpack<<<dim3(48), 256, 0, stream>>>(Wa, Wb, Wd, wab, wdb);
        ka_gram_mfma<true><<<dim3(75, 64), 256, 0, stream>>>(
            x, xbp, wab, Wa, ba, Wb, bb, ws + WS_ATT);
        kb_softmax<true><<<dim3(192), 64, 0, stream>>>(ws + WS_ATT, A, PA, attb);
        k3_y_mfma<<<dim3(25, 64), 512, 0, stream>>>(xbp, wdb, attb, out, ws + WS_SUM);
    } else {
        ka_gram_mfma<false><<<dim3(75, 64), 256, 0, stream>>>(
            x, nullptr, nullptr, Wa, ba, Wb, bb, ws + WS_ATT);
        kb_softmax<false><<<dim3(192), 64, 0, stream>>>(ws + WS_ATT, A, PA, nullptr);
        k3_y_mfma_fb<<<dim3(75, 64, 2), 256, 0, stream>>>(
            x, Wd, ws + WS_ATT, out, ws + WS_SUM);
    }
    k3b_stats<<<dim3(1), 64, 0, stream>>>(ws);
    k4_bn<<<dim3(8, 64, 64), 256, 0, stream>>>(out, x, gamma, beta, ws);
}

// Round 6
// 483.397 us; speedup vs baseline: 1.0335x; 1.0335x over previous
//
#include <hip/hip_runtime.h>
#include <math.h>

// Problem constants
constexpr int Nn = 64, Cc = 64, Tt = 300, Vv = 25, Ss = 3, Ii = 16, Oo = 64;
constexpr int TVc  = Tt * Vv;      // 7500
constexpr int CTVc = Cc * TVc;     // 480000 floats per n-slice of x
constexpr float KINV = 1.0f / 4800.0f;   // 1/(INTER*T)

// ws layout (floats)
constexpr int WS_ATT  = 0;         // N*S*25*25 = 120000 (atomic tier only)
constexpr int WS_SUM  = 120000;    // 8 copies x 64
constexpr int WS_SQ   = 120512;    // 8 copies x 64
constexpr int WS_MEAN = 121024;    // 64
constexpr int WS_RSTD = 121088;    // 64
constexpr int WS_ZERO_FLOATS = 121024;   // att + sum + sq (atomic tier)
constexpr int WS_XB_F   = 121152;  // xb bf16 [n][t*v][c]: 30,720,000 shorts
constexpr int WS_WAB_F  = WS_XB_F + 15360000;   // wab bf16 [3][32][64]
constexpr int WS_WDB_F  = WS_WAB_F + 3072;      // wdb bf16 [3][64][64]
constexpr int WS_ATTB_F = WS_WDB_F + 6144;      // attb bf16 [192][32][32]
constexpr int WS_END_F  = WS_ATTB_F + 98304;
constexpr size_t WS_NEED = (size_t)WS_END_F * 4;
// gram partials: [n][bx 75][s][625] floats = 9,000,000 (36 MB)
constexpr int WS_PART_F = WS_END_F;
constexpr size_t WS_NEED2 = (size_t)(WS_PART_F + 9000000) * 4;

typedef __attribute__((ext_vector_type(8))) short bf16x8;
typedef __attribute__((ext_vector_type(4))) short short4v;
typedef __attribute__((ext_vector_type(4))) float f32x4;
typedef __attribute__((ext_vector_type(16))) float f32x16;
typedef __attribute__((ext_vector_type(4))) int int4v;

__device__ __forceinline__ short f2bf(float f) {
    unsigned u = __builtin_bit_cast(unsigned, f);
    u += 0x7FFFu + ((u >> 16) & 1u);           // RNE
    return (short)(u >> 16);
}
__device__ __forceinline__ float bf2f(short s) {
    unsigned u = ((unsigned)(unsigned short)s) << 16;
    return __builtin_bit_cast(float, u);
}
__device__ __forceinline__ void store4(float* p, f32x4 v) {
    __builtin_memcpy(p, &v, 16);
}

// ---------------------------------------------------------------------------
// Kernel 0: x [n][c][t*v] f32 -> xb [n][t*v][c] bf16 (coalesced reads).
// ---------------------------------------------------------------------------
__global__ __launch_bounds__(256) void k0_xpose(
    const float* __restrict__ x, short* __restrict__ xb)
{
    const int n   = blockIdx.y;
    const int tid = threadIdx.x;
    const int tv  = blockIdx.x * 32 + (tid & 31);
    const int g   = (tid >> 5) & 7;
    if (tv >= TVc) return;
    const float* xp = x + (size_t)n * CTVc + (size_t)(g * 8) * TVc + tv;
    bf16x8 o;
    #pragma unroll
    for (int j = 0; j < 8; ++j) o[j] = f2bf(xp[(size_t)j * TVc]);
    *(bf16x8*)(xb + ((size_t)n * TVc + tv) * 64 + g * 8) = o;
}

// ---------------------------------------------------------------------------
// Kernel P: pack weights to bf16 once.
// ---------------------------------------------------------------------------
__global__ __launch_bounds__(256) void kpack(
    const float* __restrict__ Wa, const float* __restrict__ Wb,
    const float* __restrict__ Wd, short* __restrict__ wab, short* __restrict__ wdb)
{
    const int i = blockIdx.x * 256 + threadIdx.x;
    if (i < 6144) {
        const int s = i >> 11, rb = i & 2047, r = rb >> 6, c = rb & 63;
        const float v = (r < 16) ? Wa[(s * 16 + r) * 64 + c]
                                 : Wb[(s * 16 + (r - 16)) * 64 + c];
        wab[i] = f2bf(v);
    }
    if (i < 12288) wdb[i] = f2bf(Wd[i]);
}

// ---------------------------------------------------------------------------
// Shared phase-1 B-fragment loader (fallback kernels)
// ---------------------------------------------------------------------------
template<bool XB>
__device__ __forceinline__ void load_xfrag(
    const float* __restrict__ xn, const short* __restrict__ xbn,
    int tv, bool ok, int quad, bf16x8& b0, bf16x8& b1)
{
    if constexpr (XB) {
        const short* bp = xbn + (ok ? tv : 0) * 64 + quad * 8;
        b0 = *(const bf16x8*)bp;
        b1 = *(const bf16x8*)(bp + 32);
    } else {
        const float* bp = xn + (quad * 8) * TVc + tv;
        #pragma unroll
        for (int j = 0; j < 8; ++j) {
            b0[j] = f2bf(ok ? bp[j * TVc] : 0.0f);
            b1[j] = f2bf(ok ? bp[(j + 32) * TVc] : 0.0f);
        }
    }
}

// ---------------------------------------------------------------------------
// Kernel A (atomic tiers): MFMA conv + MFMA gram, atomicAdd into att.
// ---------------------------------------------------------------------------
template<bool XB>
__global__ __launch_bounds__(256) void ka_gram_mfma(
    const float* __restrict__ x, const short* __restrict__ xb,
    const short* __restrict__ wab,
    const float* __restrict__ Wa, const float* __restrict__ ba,
    const float* __restrict__ Wb, const float* __restrict__ bb,
    float* __restrict__ att)
{
    __shared__ short uT[112 * 104];
    __shared__ float part[4 * 1024];
    __shared__ float bab[96];

    const int tid = threadIdx.x;
    const int t0  = blockIdx.x * 4;
    const int n   = blockIdx.y;
    const float* xn  = x + n * CTVc + t0 * 25;
    const short* xbn = XB ? (xb + ((size_t)n * TVc + t0 * 25) * 64) : nullptr;

    if (tid < 96) {
        const int s = tid >> 5, r = tid & 31;
        bab[tid] = (r < 16) ? ba[s * 16 + r] : bb[s * 16 + r - 16];
    }

    const int lane = tid & 63;
    const int wave = tid >> 6;
    const int l16  = lane & 15;
    const int quad = lane >> 4;

    bf16x8 afr[3][2][2];
    #pragma unroll
    for (int s = 0; s < 3; ++s)
        #pragma unroll
        for (int half = 0; half < 2; ++half)
            #pragma unroll
            for (int k = 0; k < 2; ++k) {
                if constexpr (XB) {
                    afr[s][half][k] = *(const bf16x8*)(
                        wab + (s * 32 + half * 16 + l16) * 64 + k * 32 + quad * 8);
                } else {
                    const float* W = half ? Wb : Wa;
                    const float* wp = W + (s * 16 + l16) * 64 + k * 32 + quad * 8;
                    const float4 w0 = *(const float4*)wp;
                    const float4 w1 = *(const float4*)(wp + 4);
                    bf16x8 a;
                    a[0] = f2bf(w0.x); a[1] = f2bf(w0.y); a[2] = f2bf(w0.z); a[3] = f2bf(w0.w);
                    a[4] = f2bf(w1.x); a[5] = f2bf(w1.y); a[6] = f2bf(w1.z); a[7] = f2bf(w1.w);
                    afr[s][half][k] = a;
                }
            }
    __syncthreads();

    for (int nt = wave; nt < 7; nt += 4) {
        const int tv = nt * 16 + l16;
        const bool ok = tv < 100;
        bf16x8 b0, b1;
        load_xfrag<XB>(xn, xbn, tv, ok, quad, b0, b1);
        #pragma unroll
        for (int s = 0; s < 3; ++s)
            #pragma unroll
            for (int half = 0; half < 2; ++half) {
                f32x4 acc = {0.0f, 0.0f, 0.0f, 0.0f};
                acc = __builtin_amdgcn_mfma_f32_16x16x32_bf16(afr[s][half][0], b0, acc, 0, 0, 0);
                acc = __builtin_amdgcn_mfma_f32_16x16x32_bf16(afr[s][half][1], b1, acc, 0, 0, 0);
                const float4 bv = *(const float4*)(bab + s * 32 + half * 16 + quad * 4);
                short4v pk;
                pk[0] = f2bf(acc[0] + bv.x); pk[1] = f2bf(acc[1] + bv.y);
                pk[2] = f2bf(acc[2] + bv.z); pk[3] = f2bf(acc[3] + bv.w);
                *(short4v*)(uT + tv * 104 + s * 32 + half * 16 + quad * 4) = pk;
            }
    }
    __syncthreads();

    const int t   = wave;
    const int w32 = lane & 31;
    const int khi = lane >> 5;
    f32x16 g[3];
    #pragma unroll
    for (int s = 0; s < 3; ++s)
        #pragma unroll
        for (int r = 0; r < 16; ++r) g[s][r] = 0.0f;

    #pragma unroll
    for (int s = 0; s < 3; ++s) {
        const short* base = uT + (t * 25 + w32) * 104 + s * 32 + khi * 8;
        const bf16x8 aA = *(const bf16x8*)(base);
        const bf16x8 bB = *(const bf16x8*)(base + 16);
        g[s] = __builtin_amdgcn_mfma_f32_32x32x16_bf16(aA, bB, g[s], 0, 0, 0);
    }

    for (int s = 0; s < 3; ++s) {
        __syncthreads();
        #pragma unroll
        for (int r = 0; r < 16; ++r) {
            const int row = (r & 3) + 8 * (r >> 2) + 4 * khi;
            part[wave * 1024 + row * 32 + w32] = g[s][r];
        }
        __syncthreads();
        float* attns = att + (n * 3 + s) * 625;
        for (int p = tid; p < 625; p += 256) {
            const int v = p / 25, w = p - v * 25;
            const int q = v * 32 + w;
            atomicAdd(attns + p, part[q] + part[1024 + q] + part[2048 + q] + part[3072 + q]);
        }
    }
}

// ---------------------------------------------------------------------------
// Kernel A' (partial tier): same math, but per-block COALESCED partial writes
// (no global atomics). partp[((n*75+bx)*3+s)*625 + p].
// ---------------------------------------------------------------------------
__global__ __launch_bounds__(256) void ka_gram_part(
    const short* __restrict__ xb, const short* __restrict__ wab,
    const float* __restrict__ ba, const float* __restrict__ bb,
    float* __restrict__ partp)
{
    __shared__ short uT[112 * 104];
    __shared__ float part[4 * 1024];
    __shared__ float bab[96];

    const int tid = threadIdx.x;
    const int bx  = blockIdx.x;
    const int n   = blockIdx.y;
    const short* xbn = xb + ((size_t)n * TVc + bx * 100) * 64;

    if (tid < 96) {
        const int s = tid >> 5, r = tid & 31;
        bab[tid] = (r < 16) ? ba[s * 16 + r] : bb[s * 16 + r - 16];
    }

    const int lane = tid & 63;
    const int wave = tid >> 6;
    const int l16  = lane & 15;
    const int quad = lane >> 4;

    bf16x8 afr[3][2][2];
    #pragma unroll
    for (int s = 0; s < 3; ++s)
        #pragma unroll
        for (int half = 0; half < 2; ++half)
            #pragma unroll
            for (int k = 0; k < 2; ++k)
                afr[s][half][k] = *(const bf16x8*)(
                    wab + (s * 32 + half * 16 + l16) * 64 + k * 32 + quad * 8);
    __syncthreads();

    for (int nt = wave; nt < 7; nt += 4) {
        const int tv = nt * 16 + l16;
        const bool ok = tv < 100;
        const short* bp = xbn + (ok ? tv : 0) * 64 + quad * 8;
        const bf16x8 b0 = *(const bf16x8*)bp;
        const bf16x8 b1 = *(const bf16x8*)(bp + 32);
        #pragma unroll
        for (int s = 0; s < 3; ++s)
            #pragma unroll
            for (int half = 0; half < 2; ++half) {
                f32x4 acc = {0.0f, 0.0f, 0.0f, 0.0f};
                acc = __builtin_amdgcn_mfma_f32_16x16x32_bf16(afr[s][half][0], b0, acc, 0, 0, 0);
                acc = __builtin_amdgcn_mfma_f32_16x16x32_bf16(afr[s][half][1], b1, acc, 0, 0, 0);
                const float4 bv = *(const float4*)(bab + s * 32 + half * 16 + quad * 4);
                short4v pk;
                pk[0] = f2bf(acc[0] + bv.x); pk[1] = f2bf(acc[1] + bv.y);
                pk[2] = f2bf(acc[2] + bv.z); pk[3] = f2bf(acc[3] + bv.w);
                if (ok)
                    *(short4v*)(uT + tv * 104 + s * 32 + half * 16 + quad * 4) = pk;
            }
    }
    __syncthreads();

    const int t   = wave;
    const int w32 = lane & 31;
    const int khi = lane >> 5;
    f32x16 g[3];
    #pragma unroll
    for (int s = 0; s < 3; ++s)
        #pragma unroll
        for (int r = 0; r < 16; ++r) g[s][r] = 0.0f;

    #pragma unroll
    for (int s = 0; s < 3; ++s) {
        const short* base = uT + (t * 25 + w32) * 104 + s * 32 + khi * 8;
        const bf16x8 aA = *(const bf16x8*)(base);
        const bf16x8 bB = *(const bf16x8*)(base + 16);
        g[s] = __builtin_amdgcn_mfma_f32_32x32x16_bf16(aA, bB, g[s], 0, 0, 0);
    }

    for (int s = 0; s < 3; ++s) {
        __syncthreads();
        #pragma unroll
        for (int r = 0; r < 16; ++r) {
            const int row = (r & 3) + 8 * (r >> 2) + 4 * khi;
            part[wave * 1024 + row * 32 + w32] = g[s][r];
        }
        __syncthreads();
        float* po = partp + ((size_t)(n * 75 + bx) * 3 + s) * 625;
        for (int p = tid; p < 625; p += 256) {
            const int v = p / 25, w = p - v * 25;
            const int q = v * 32 + w;
            po[p] = part[q] + part[1024 + q] + part[2048 + q] + part[3072 + q];
        }
    }
}

// NOTE (ka_gram_part vs ka_gram_mfma): uT store moved under `if (ok)` guard —
// identical semantics (tv>=100 rows of uT are never read by the gram phase,
// which uses rows t*25+w32 < 100).

// ---------------------------------------------------------------------------
// Kernel B (atomic tiers): column softmax (+ optional attb emit).
// ---------------------------------------------------------------------------
template<bool ATTB>
__global__ __launch_bounds__(64) void kb_softmax(
    float* __restrict__ att, const float* __restrict__ A, const float* __restrict__ PA,
    short* __restrict__ attb)
{
    const int b = blockIdx.x;
    const int s = b % 3;
    const int w = threadIdx.x;
    if (w >= 32) return;
    float col[25] = {};
    if (w < 25) {
        float* base = att + b * 625;
        float m = -1e30f;
        #pragma unroll
        for (int v = 0; v < 25; ++v) {
            col[v] = base[v * 25 + w] * KINV;
            m = fmaxf(m, col[v]);
        }
        float sum = 0.0f;
        #pragma unroll
        for (int v = 0; v < 25; ++v) { col[v] = expf(col[v] - m); sum += col[v]; }
        const float inv = 1.0f / sum;
        #pragma unroll
        for (int v = 0; v < 25; ++v) {
            col[v] = fmaf(col[v], inv, A[(s * 25 + v) * 25 + w] + PA[(s * 25 + v) * 25 + w]);
            base[v * 25 + w] = col[v];
        }
    }
    if constexpr (ATTB) {
        short* dst = attb + b * 1024 + w * 32;
        #pragma unroll
        for (int v = 0; v < 25; ++v) dst[v] = (w < 25) ? f2bf(col[v]) : (short)0;
        #pragma unroll
        for (int v = 25; v < 32; ++v) dst[v] = 0;
    }
}

// ---------------------------------------------------------------------------
// Kernel B' (partial tier): reduce 75 partials + softmax + attb, one launch.
// ---------------------------------------------------------------------------
__global__ __launch_bounds__(256) void kb_fuse(
    const float* __restrict__ partp, const float* __restrict__ A,
    const float* __restrict__ PA, short* __restrict__ attb)
{
    __shared__ float att_s[625];
    const int b = blockIdx.x;              // n*3 + s
    const int n = b / 3, s = b - n * 3;
    const int tid = threadIdx.x;

    const float* pp = partp + (size_t)n * 75 * 1875 + s * 625;
    for (int p = tid; p < 625; p += 256) {
        float acc = 0.0f;
        #pragma unroll 5
        for (int bx = 0; bx < 75; ++bx) acc += pp[(size_t)bx * 1875 + p];
        att_s[p] = acc;
    }
    __syncthreads();

    if (tid < 32) {
        const int w = tid;
        float col[25] = {};
        if (w < 25) {
            float m = -1e30f;
            #pragma unroll
            for (int v = 0; v < 25; ++v) {
                col[v] = att_s[v * 25 + w] * KINV;
                m = fmaxf(m, col[v]);
            }
            float sum = 0.0f;
            #pragma unroll
            for (int v = 0; v < 25; ++v) { col[v] = expf(col[v] - m); sum += col[v]; }
            const float inv = 1.0f / sum;
            #pragma unroll
            for (int v = 0; v < 25; ++v)
                col[v] = fmaf(col[v], inv, A[(s * 25 + v) * 25 + w] + PA[(s * 25 + v) * 25 + w]);
        }
        short* dst = attb + b * 1024 + w * 32;
        #pragma unroll
        for (int v = 0; v < 25; ++v) dst[v] = (w < 25) ? f2bf(col[v]) : (short)0;
        #pragma unroll
        for (int v = 25; v < 32; ++v) dst[v] = 0;
    }
}

// ---------------------------------------------------------------------------
// Kernel 3 (r5->r6): grid (75,64) single tile (r4 structure), PLUS:
//  - y-tile staged in LDS (reusing U) and written COALESCED as float4
//    (was: 64 lanes x 16B to 64 different 30KB-strided rows = 64 line-touches
//    per store instr; now ~10 contiguous lines per instr).
//  - attb frags + x frag loaded before the zero loop (latency cover).
// Barriers: 4 (zero | phase1 | phase2-done/bn-visible | yS-ready).
// ---------------------------------------------------------------------------
__global__ __launch_bounds__(512, 6) void k3_y_mfma(
    const short* __restrict__ xb, const short* __restrict__ wdb,
    const short* __restrict__ attb, float* __restrict__ y, float* __restrict__ bns)
{
    __shared__ __align__(16) short U[192 * 128];     // 49.2 KB; reused as yS f32[6400]
    __shared__ float bnA[8][32], bnB[8][32];         // 2 KB

    const int tid = threadIdx.x;
    const int bx  = blockIdx.x;
    const int n   = blockIdx.y;

    const int lane = tid & 63;
    const int wave = tid >> 6;
    const int l16  = lane & 15;
    const int quad = lane >> 4;

    // early loads: x fragment + attb fragments (cover latency under zeroing)
    const int tv  = (wave < 7) ? wave * 16 + l16 : 0;
    const bool ok = (wave < 7) && (tv < 100);
    const short* xbn = xb + ((size_t)n * TVc + bx * 100) * 64;
    const int xoff = (ok ? tv : 0) * 64 + quad * 8;
    const bf16x8 bc0 = *(const bf16x8*)(xbn + xoff);
    const bf16x8 bc1 = *(const bf16x8*)(xbn + xoff + 32);

    bf16x8 a0[3], a1[3];
    #pragma unroll
    for (int s = 0; s < 3; ++s) {
        const short* ab = attb + (size_t)(n * 3 + s) * 1024 + l16 * 32 + quad * 8;
        a0[s] = *(const bf16x8*)ab;
        a1[s] = *(const bf16x8*)(ab + 512);
    }

    const int tl  = tv / 25;
    const int vp  = tv - tl * 25;
    const int col = tl * 32 + vp;
    const int grp = col >> 3, ing = col & 7;

    // zero ALL of U (pad cols must be exact 0.0 for phase-2 K-dim)
    for (int i = tid; i < 3072; i += 512)
        ((int4v*)U)[i] = (int4v){0, 0, 0, 0};
    __syncthreads();

    // ---- phase 1 (waves 0..6) ----
    if (wave < 7) {
        #pragma unroll
        for (int s = 0; s < 3; ++s)
            #pragma unroll
            for (int m = 0; m < 4; ++m) {
                const short* wp = wdb + (s * 64 + m * 16 + l16) * 64 + quad * 8;
                const bf16x8 f0 = *(const bf16x8*)wp;
                const bf16x8 f1 = *(const bf16x8*)(wp + 32);
                f32x4 acc = {0.0f, 0.0f, 0.0f, 0.0f};
                acc = __builtin_amdgcn_mfma_f32_16x16x32_bf16(f0, bc0, acc, 0, 0, 0);
                acc = __builtin_amdgcn_mfma_f32_16x16x32_bf16(f1, bc1, acc, 0, 0, 0);
                if (ok) {
                    #pragma unroll
                    for (int r = 0; r < 4; ++r) {
                        const int row = s * 64 + m * 16 + quad * 4 + r;
                        U[row * 128 + (((grp ^ (row & 15)) << 3) | ing)] = f2bf(acc[r]);
                    }
                }
            }
    }
    __syncthreads();

    // ---- phase 2 ----
    const int t  = wave >> 1;
    const int ob = (wave & 1) * 32;
    f32x4 D[2][2];
    #pragma unroll
    for (int mt = 0; mt < 2; ++mt)
        #pragma unroll
        for (int nb = 0; nb < 2; ++nb) D[mt][nb] = (f32x4){0.0f, 0.0f, 0.0f, 0.0f};
    #pragma unroll
    for (int s = 0; s < 3; ++s) {
        #pragma unroll
        for (int nb = 0; nb < 2; ++nb) {
            const int row = s * 64 + ob + nb * 16 + l16;
            const bf16x8 bv = *(const bf16x8*)(
                U + row * 128 + (((t * 4 + quad) ^ (row & 15)) << 3));
            D[0][nb] = __builtin_amdgcn_mfma_f32_16x16x32_bf16(a0[s], bv, D[0][nb], 0, 0, 0);
            D[1][nb] = __builtin_amdgcn_mfma_f32_16x16x32_bf16(a1[s], bv, D[1][nb], 0, 0, 0);
        }
    }
    __syncthreads();   // all U reads complete before yS overwrites it

    // ---- stage y-tile in LDS + BN accumulation from registers ----
    float* yS = (float*)U;   // [64 og][100 c]  (25.6 KB)
    float s1[2] = {0.0f, 0.0f}, s2[2] = {0.0f, 0.0f};
    #pragma unroll
    for (int nb = 0; nb < 2; ++nb) {
        const int og = ob + nb * 16 + l16;
        const int base = og * 100 + t * 25;
        const f32x4 d0 = D[0][nb];
        #pragma unroll
        for (int j = 0; j < 4; ++j) yS[base + quad * 4 + j] = d0[j];
        s1[nb] += d0[0] + d0[1] + d0[2] + d0[3];
        s2[nb] += d0[0]*d0[0] + d0[1]*d0[1] + d0[2]*d0[2] + d0[3]*d0[3];
        const f32x4 d1 = D[1][nb];
        if (quad < 2) {
            #pragma unroll
            for (int j = 0; j < 4; ++j) yS[base + 16 + quad * 4 + j] = d1[j];
            s1[nb] += d1[0] + d1[1] + d1[2] + d1[3];
            s2[nb] += d1[0]*d1[0] + d1[1]*d1[1] + d1[2]*d1[2] + d1[3]*d1[3];
        } else if (quad == 2) {
            yS[base + 24] = d1[0];
            s1[nb] += d1[0];
            s2[nb] += d1[0] * d1[0];
        }
    }
    #pragma unroll
    for (int nb = 0; nb < 2; ++nb) {
        s1[nb] += __shfl_xor(s1[nb], 16); s1[nb] += __shfl_xor(s1[nb], 32);
        s2[nb] += __shfl_xor(s2[nb], 16); s2[nb] += __shfl_xor(s2[nb], 32);
    }
    if (lane < 16) {
        bnA[wave][lane]      = s1[0];
        bnA[wave][16 + lane] = s1[1];
        bnB[wave][lane]      = s2[0];
        bnB[wave][16 + lane] = s2[1];
    }
    __syncthreads();   // yS complete + bnA/bnB visible

    // ---- coalesced y store: 1600 float4 = [og][c4], contiguous per og ----
    {
        f32x4* y4 = (f32x4*)y;
        const f32x4* ysv = (const f32x4*)yS;
        const size_t obase = (size_t)n * 64 * 1875 + (size_t)bx * 25;
        for (int i4 = tid; i4 < 1600; i4 += 512) {
            const int og = i4 / 25;
            const int c4 = i4 - og * 25;
            y4[obase + (size_t)og * 1875 + c4] = ysv[i4];
        }
    }
    if (tid < 64) {
        const int o = tid, h = o >> 5, i = o & 31;
        const float S1 = bnA[h][i] + bnA[h + 2][i] + bnA[h + 4][i] + bnA[h + 6][i];
        const float S2 = bnB[h][i] + bnB[h + 2][i] + bnB[h + 4][i] + bnB[h + 6][i];
        const int cp = (bx & 7) * 64;
        atomicAdd(bns + cp + o, S1);
        atomicAdd(bns + 512 + cp + o, S2);
    }
}

// ---------------------------------------------------------------------------
// Kernel 3 fallback (ws too small): round-1 structure, f32 inputs.
// ---------------------------------------------------------------------------
__global__ __launch_bounds__(256) void k3_y_mfma_fb(
    const float* __restrict__ x, const float* __restrict__ Wd,
    const float* __restrict__ att, float* __restrict__ y, float* __restrict__ bns)
{
    __shared__ __align__(16) short U[96 * 128];
    __shared__ __align__(16) short attT[3 * 1024];
    __shared__ float bn1[4][32], bn2[4][32];

    const int tid = threadIdx.x;
    const int t0  = blockIdx.x * 4;
    const int n   = blockIdx.y;
    const int oh  = blockIdx.z;
    const float* xn = x + n * CTVc + t0 * 25;

    const int lane = tid & 63;
    const int wave = tid >> 6;
    const int l16  = lane & 15;
    const int quad = lane >> 4;

    for (int i = tid; i < 1536; i += 256)
        ((int4v*)U)[i] = (int4v){0, 0, 0, 0};
    for (int i = tid; i < 3072; i += 256) {
        const int s = i >> 10, r = i & 1023, v = r >> 5, vp = r & 31;
        const float val = (v < 25 && vp < 25) ? att[(n * 3 + s) * 625 + vp * 25 + v] : 0.0f;
        attT[i] = f2bf(val);
    }
    bf16x8 afr[3][2][2];
    #pragma unroll
    for (int s = 0; s < 3; ++s)
        #pragma unroll
        for (int m = 0; m < 2; ++m)
            #pragma unroll
            for (int k = 0; k < 2; ++k) {
                const float* wp = Wd + ((s * 64 + oh * 32 + m * 16 + l16) * 64) + k * 32 + quad * 8;
                const float4 w0 = *(const float4*)wp;
                const float4 w1 = *(const float4*)(wp + 4);
                bf16x8 a;
                a[0] = f2bf(w0.x); a[1] = f2bf(w0.y); a[2] = f2bf(w0.z); a[3] = f2bf(w0.w);
                a[4] = f2bf(w1.x); a[5] = f2bf(w1.y); a[6] = f2bf(w1.z); a[7] = f2bf(w1.w);
                afr[s][m][k] = a;
            }
    __syncthreads();

    for (int nt = wave; nt < 7; nt += 4) {
        const int tv = nt * 16 + l16;
        const bool ok = tv < 100;
        bf16x8 b0, b1;
        load_xfrag<false>(xn, nullptr, tv, ok, quad, b0, b1);
        const int tl  = tv / 25;
        const int vp  = tv - tl * 25;
        const int col = tl * 32 + vp;
        const int grp = col >> 3, ing = col & 7;
        #pragma unroll
        for (int s = 0; s < 3; ++s)
            #pragma unroll
            for (int m = 0; m < 2; ++m) {
                f32x4 acc = {0.0f, 0.0f, 0.0f, 0.0f};
                acc = __builtin_amdgcn_mfma_f32_16x16x32_bf16(afr[s][m][0], b0, acc, 0, 0, 0);
                acc = __builtin_amdgcn_mfma_f32_16x16x32_bf16(afr[s][m][1], b1, acc, 0, 0, 0);
                if (ok) {
                    #pragma unroll
                    for (int r = 0; r < 4; ++r) {
                        const int row = s * 32 + m * 16 + quad * 4 + r;
                        U[row * 128 + (((grp ^ (row & 15)) << 3) | ing)] = f2bf(acc[r]);
                    }
                }
            }
    }
    __syncthreads();

    const int t = wave;
    bf16x8 aF[3][2], bF[3][2];
    #pragma unroll
    for (int s = 0; s < 3; ++s) {
        #pragma unroll
        for (int mt = 0; mt < 2; ++mt)
            aF[s][mt] = *(const bf16x8*)(attT + s * 1024 + (mt * 16 + l16) * 32 + quad * 8);
        #pragma unroll
        for (int nb = 0; nb < 2; ++nb) {
            const int row = s * 32 + nb * 16 + l16;
            bF[s][nb] = *(const bf16x8*)(U + row * 128 + (((t * 4 + quad) ^ (row & 15)) << 3));
        }
    }
    f32x4 D[2][2];
    #pragma unroll
    for (int mt = 0; mt < 2; ++mt)
        #pragma unroll
        for (int nb = 0; nb < 2; ++nb) D[mt][nb] = (f32x4){0.0f, 0.0f, 0.0f, 0.0f};
    #pragma unroll
    for (int s = 0; s < 3; ++s)
        #pragma unroll
        for (int mt = 0; mt < 2; ++mt)
            #pragma unroll
            for (int nb = 0; nb < 2; ++nb)
                D[mt][nb] = __builtin_amdgcn_mfma_f32_16x16x32_bf16(aF[s][mt], bF[s][nb], D[mt][nb], 0, 0, 0);

    float s1[2] = {0.0f, 0.0f}, s2[2] = {0.0f, 0.0f};
    #pragma unroll
    for (int nb = 0; nb < 2; ++nb) {
        const int og = oh * 32 + nb * 16 + l16;
        float* dst = y + ((size_t)(n * 64 + og) * 300 + t0 + t) * 25;
        const f32x4 d0 = D[0][nb];
        store4(dst + quad * 4, d0);
        s1[nb] += d0[0] + d0[1] + d0[2] + d0[3];
        s2[nb] += d0[0]*d0[0] + d0[1]*d0[1] + d0[2]*d0[2] + d0[3]*d0[3];
        const f32x4 d1 = D[1][nb];
        if (quad < 2) {
            store4(dst + 16 + quad * 4, d1);
            s1[nb] += d1[0] + d1[1] + d1[2] + d1[3];
            s2[nb] += d1[0]*d1[0] + d1[1]*d1[1] + d1[2]*d1[2] + d1[3]*d1[3];
        } else if (quad == 2) {
            dst[24] = d1[0];
            s1[nb] += d1[0];
            s2[nb] += d1[0] * d1[0];
        }
    }
    #pragma unroll
    for (int nb = 0; nb < 2; ++nb) {
        s1[nb] += __shfl_xor(s1[nb], 16); s1[nb] += __shfl_xor(s1[nb], 32);
        s2[nb] += __shfl_xor(s2[nb], 16); s2[nb] += __shfl_xor(s2[nb], 32);
    }
    if (lane < 16) {
        bn1[wave][lane]      = s1[0];
        bn1[wave][16 + lane] = s1[1];
        bn2[wave][lane]      = s2[0];
        bn2[wave][16 + lane] = s2[1];
    }
    __syncthreads();
    if (tid < 32) {
        const float S1 = bn1[0][tid] + bn1[1][tid] + bn1[2][tid] + bn1[3][tid];
        const float S2 = bn2[0][tid] + bn2[1][tid] + bn2[2][tid] + bn2[3][tid];
        const int cp = (blockIdx.x & 7) * 64;
        atomicAdd(bns + cp + oh * 32 + tid, S1);
        atomicAdd(bns + 512 + cp + oh * 32 + tid, S2);
    }
}

// ---------------------------------------------------------------------------
// Kernel 3b: finalize BN stats (8-copy reduction)
// ---------------------------------------------------------------------------
__global__ __launch_bounds__(64) void k3b_stats(float* __restrict__ ws)
{
    const int o = threadIdx.x;
    if (o >= 64) return;
    const float cnt_inv = 1.0f / 480000.0f;
    float s = 0.0f, q = 0.0f;
    #pragma unroll
    for (int j = 0; j < 8; ++j) {
        s += ws[WS_SUM + j * 64 + o];
        q += ws[WS_SQ  + j * 64 + o];
    }
    const float mean = s * cnt_inv;
    const float var  = q * cnt_inv - mean * mean;
    ws[WS_MEAN + o] = mean;
    ws[WS_RSTD + o] = rsqrtf(var + 1e-5f);
}

// ---------------------------------------------------------------------------
// Kernel 4: BN + residual + ReLU — grid-stride (G11), ~15 float4/thread.
// ---------------------------------------------------------------------------
__global__ __launch_bounds__(256) void k4_bn(
    float* __restrict__ out, const float* __restrict__ x,
    const float* __restrict__ gamma, const float* __restrict__ beta,
    const float* __restrict__ ws)
{
    const int stride = gridDim.x * 256;
    for (int i4 = blockIdx.x * 256 + threadIdx.x; i4 < 7680000; i4 += stride) {
        const int o = (i4 / 1875) & 63;
        const float mean = ws[WS_MEAN + o], rstd = ws[WS_RSTD + o];
        const float g = gamma[o], b = beta[o];
        const float4 yv = ((const float4*)out)[i4];
        const float4 xv = ((const float4*)x)[i4];
        float4 r;
        r.x = fmaxf(fmaf(g * (yv.x - mean), rstd, b) + xv.x, 0.0f);
        r.y = fmaxf(fmaf(g * (yv.y - mean), rstd, b) + xv.y, 0.0f);
        r.z = fmaxf(fmaf(g * (yv.z - mean), rstd, b) + xv.z, 0.0f);
        r.w = fmaxf(fmaf(g * (yv.w - mean), rstd, b) + xv.w, 0.0f);
        ((float4*)out)[i4] = r;
    }
}

// ---------------------------------------------------------------------------
extern "C" void kernel_launch(void* const* d_in, const int* in_sizes, int n_in,
                              void* d_out, int out_size, void* d_ws, size_t ws_size,
                              hipStream_t stream)
{
    const float* x  = (const float*)d_in[0];
    const float* A  = (const float*)d_in[1];
    const float* PA = (const float*)d_in[2];
    const float* Wa = (const float*)d_in[3];
    const float* ba = (const float*)d_in[4];
    const float* Wb = (const float*)d_in[5];
    const float* bb = (const float*)d_in[6];
    const float* Wd = (const float*)d_in[7];
    const float* gamma = (const float*)d_in[9];
    const float* beta  = (const float*)d_in[10];
    float* out = (float*)d_out;
    float* ws  = (float*)d_ws;

    if (ws_size >= WS_NEED2) {
        // ---- partial-reduction tier: no gram atomics ----
        hipMemsetAsync(ws + WS_SUM, 0, 1024 * sizeof(float), stream);
        short* xbp  = (short*)(ws + WS_XB_F);
        short* wab  = (short*)(ws + WS_WAB_F);
        short* wdb  = (short*)(ws + WS_WDB_F);
        short* attb = (short*)(ws + WS_ATTB_F);
        float* partp = ws + WS_PART_F;
        k0_xpose<<<dim3(235, 64), 256, 0, stream>>>(x, xbp);
        kpack<<<dim3(48), 256, 0, stream>>>(Wa, Wb, Wd, wab, wdb);
        ka_gram_part<<<dim3(75, 64), 256, 0, stream>>>(xbp, wab, ba, bb, partp);
        kb_fuse<<<dim3(192), 256, 0, stream>>>(partp, A, PA, attb);
        k3_y_mfma<<<dim3(75, 64), 512, 0, stream>>>(xbp, wdb, attb, out, ws + WS_SUM);
    } else if (ws_size >= WS_NEED) {
        // ---- atomic tier (r4-verified path) ----
        hipMemsetAsync(d_ws, 0, (size_t)WS_ZERO_FLOATS * sizeof(float), stream);
        short* xbp  = (short*)(ws + WS_XB_F);
        short* wab  = (short*)(ws + WS_WAB_F);
        short* wdb  = (short*)(ws + WS_WDB_F);
        short* attb = (short*)(ws + WS_ATTB_F);
        k0_xpose<<<dim3(235, 64), 256, 0, stream>>>(x, xbp);
        kpack<<<dim3(48), 256, 0, stream>>>(Wa, Wb, Wd, wab, wdb);
        ka_gram_mfma<true><<<dim3(75, 64), 256, 0, stream>>>(
            x, xbp, wab, Wa, ba, Wb, bb, ws + WS_ATT);
        kb_softmax<true><<<dim3(192), 64, 0, stream>>>(ws + WS_ATT, A, PA, attb);
        k3_y_mfma<<<dim3(75, 64), 512, 0, stream>>>(xbp, wdb, attb, out, ws + WS_SUM);
    } else {
        // ---- minimal-ws fallback ----
        hipMemsetAsync(d_ws, 0, (size_t)WS_ZERO_FLOATS * sizeof(float), stream);
        ka_gram_mfma<false><<<dim3(75, 64), 256, 0, stream>>>(
            x, nullptr, nullptr, Wa, ba, Wb, bb, ws + WS_ATT);
        kb_softmax<false><<<dim3(192), 64, 0, stream>>>(ws + WS_ATT, A, PA, nullptr);
        k3_y_mfma_fb<<<dim3(75, 64, 2), 256, 0, stream>>>(
            x, Wd, ws + WS_ATT, out, ws + WS_SUM);
    }
    k3b_stats<<<dim3(1), 64, 0, stream>>>(ws);
    k4_bn<<<dim3(2048), 256, 0, stream>>>(out, x, gamma, beta, ws);
}